// Round 2
// baseline (479.649 us; speedup 1.0000x reference)
//
#include <hip/hip_runtime.h>

// x: (4, 32, 512, 512) fp32; bias: (1,32,1,1) fp32
// out: G1 | G2 | G3 concatenated, each (4,32,512,512) fp32
//
// G1[h,w] = (h>=1 && w>=1)   ? exp(-(x[h-1,w-1]-x[h,w])^2)+b : b
// G2[h,w] = (w>=1)           ? exp(-(x[h,w-1]  -x[h,w])^2)+b : b
// G3[h,w] = (h<=510 && w>=1) ? exp(-(x[h+1,w-1]-x[h,w])^2)+b : b
//
// Memory-bound: 128 MiB read + 384 MiB write => ~85 us at 6.3 TB/s.
// R2: fully scalarized — NO local arrays / member-pointer arithmetic
// (R1 theory: those forced scratch spill -> ~1.5 GB hidden traffic).

#define IMG_W 512
#define IMG_H 512
#define PLANE (IMG_W * IMG_H)
#define N_IMG 128            // 4 * 32
#define N_ELEM (N_IMG * PLANE)

__device__ __forceinline__ float gatef(float a, float b) {
    float d = a - b;
    return __expf(-d * d);
}

__global__ __launch_bounds__(256)
void embeded_gate_kernel(const float* __restrict__ x,
                         const float* __restrict__ bias,
                         float* __restrict__ out) {
    int tid = blockIdx.x * blockDim.x + threadIdx.x;
    // one thread per float4 group: 128 groups per row
    int w4  = tid & 127;          // float4 index within row
    int row = tid >> 7;           // global row index (img*512 + h)
    int h   = row & 511;
    int img = row >> 9;           // n*32 + c
    int c   = img & 31;
    int w0  = w4 << 2;            // first column of this group

    const float b = bias[c];

    int rowc = img * PLANE + h * IMG_W;
    int hu = (h > 0)   ? h - 1 : 0;     // clamped; result masked below
    int hd = (h < 511) ? h + 1 : 511;
    int wm = (w0 > 0)  ? w0 - 1 : 0;
    int rowu = img * PLANE + hu * IMG_W;
    int rowd = img * PLANE + hd * IMG_W;

    // aligned vector loads (coalesced, 16B/lane)
    const float4 cur = *(const float4*)(x + rowc + w0);
    const float4 up  = *(const float4*)(x + rowu + w0);
    const float4 dn  = *(const float4*)(x + rowd + w0);
    // the w0-1 scalars (L1/L2 hits — same lines as neighbor threads)
    const float upm = x[rowu + wm];
    const float cum = x[rowc + wm];
    const float dnm = x[rowd + wm];

    const bool hu_ok = (h > 0);
    const bool hd_ok = (h < 511);
    const bool w_ok0 = (w0 > 0);   // only element 0 of each group can fail

    // G1 (up-left neighbor)
    float g1x = (hu_ok && w_ok0) ? gatef(upm,  cur.x) + b : b;
    float g1y = hu_ok            ? gatef(up.x, cur.y) + b : b;
    float g1z = hu_ok            ? gatef(up.y, cur.z) + b : b;
    float g1w = hu_ok            ? gatef(up.z, cur.w) + b : b;

    // G2 (left neighbor)
    float g2x = w_ok0 ? gatef(cum, cur.x) + b : b;
    float g2y = gatef(cur.x, cur.y) + b;
    float g2z = gatef(cur.y, cur.z) + b;
    float g2w = gatef(cur.z, cur.w) + b;

    // G3 (down-left neighbor)
    float g3x = (hd_ok && w_ok0) ? gatef(dnm,  cur.x) + b : b;
    float g3y = hd_ok            ? gatef(dn.x, cur.y) + b : b;
    float g3z = hd_ok            ? gatef(dn.y, cur.z) + b : b;
    float g3w = hd_ok            ? gatef(dn.z, cur.w) + b : b;

    *(float4*)(out + rowc + w0)              = make_float4(g1x, g1y, g1z, g1w);
    *(float4*)(out + N_ELEM + rowc + w0)     = make_float4(g2x, g2y, g2z, g2w);
    *(float4*)(out + 2 * N_ELEM + rowc + w0) = make_float4(g3x, g3y, g3z, g3w);
}

extern "C" void kernel_launch(void* const* d_in, const int* in_sizes, int n_in,
                              void* d_out, int out_size, void* d_ws, size_t ws_size,
                              hipStream_t stream) {
    const float* x    = (const float*)d_in[0];
    const float* bias = (const float*)d_in[1];
    float* out        = (float*)d_out;

    const int total_vec = N_ELEM / 4;          // 8,388,608 threads
    const int block = 256;
    const int grid = total_vec / block;        // 32,768 blocks
    embeded_gate_kernel<<<grid, block, 0, stream>>>(x, bias, out);
}